// Round 3
// baseline (303.950 us; speedup 1.0000x reference)
//
#include <hip/hip_runtime.h>
#include <hip/hip_bf16.h>

#define BATCH 128
#define DMEM 64
#define NMEM 4096
#define DMODEL 1024
#define ROWB 72  // bf16 elems per LDS row: 64 slots + 8 pad (144 B rows, 16B-aligned)

typedef __bf16 v8bf __attribute__((ext_vector_type(8)));
typedef float v4f __attribute__((ext_vector_type(4)));
typedef float v2f __attribute__((ext_vector_type(2)));
typedef float v16f __attribute__((ext_vector_type(16)));

// ---------------------------------------------------------------------------
// Split-K fp32 GEMM tile: C[m0+32][n0+32] += A[.][k0:k0+32*nchunks] @ W^T
// atomicAdd accumulate; bias added when non-null. 256 threads, 2x2 micro-tile.
// ---------------------------------------------------------------------------
__device__ __forceinline__ void gemm_sk(const float* __restrict__ A,
                                        const float* __restrict__ W,
                                        const float* __restrict__ bias,
                                        float* __restrict__ C,
                                        int m0, int n0, int k0, int nchunks,
                                        float* smem) {
    float(*As)[36] = (float(*)[36])smem;
    float(*Ws)[36] = (float(*)[36])(smem + 32 * 36);
    const int t = threadIdx.x;
    const int lrow = t >> 3;
    const int lc4 = (t & 7) * 4;
    const int rp = t >> 4;
    const int cp = t & 15;

    float acc00 = 0.f, acc01 = 0.f, acc10 = 0.f, acc11 = 0.f;

    v4f av = *(const v4f*)&A[(size_t)(m0 + lrow) * DMODEL + k0 + lc4];
    v4f wv = *(const v4f*)&W[(size_t)(n0 + lrow) * DMODEL + k0 + lc4];

    for (int c = 0; c < nchunks; ++c) {
        __syncthreads();
        *(v4f*)&As[lrow][lc4] = av;
        *(v4f*)&Ws[lrow][lc4] = wv;
        __syncthreads();
        if (c + 1 < nchunks) {
            const int kc = k0 + (c + 1) * 32;
            av = *(const v4f*)&A[(size_t)(m0 + lrow) * DMODEL + kc + lc4];
            wv = *(const v4f*)&W[(size_t)(n0 + lrow) * DMODEL + kc + lc4];
        }
#pragma unroll
        for (int kk = 0; kk < 32; kk += 4) {
            v4f a0 = *(v4f*)&As[rp][kk];
            v4f a1 = *(v4f*)&As[rp + 16][kk];
            v4f b0 = *(v4f*)&Ws[cp][kk];
            v4f b1 = *(v4f*)&Ws[cp + 16][kk];
#pragma unroll
            for (int q = 0; q < 4; ++q) {
                acc00 = fmaf(a0[q], b0[q], acc00);
                acc01 = fmaf(a0[q], b1[q], acc01);
                acc10 = fmaf(a1[q], b0[q], acc10);
                acc11 = fmaf(a1[q], b1[q], acc11);
            }
        }
    }
    float bv0 = 0.f, bv1 = 0.f;
    if (bias) { bv0 = bias[n0 + cp]; bv1 = bias[n0 + cp + 16]; }
    atomicAdd(&C[(size_t)(m0 + rp) * 1024 + n0 + cp], acc00 + bv0);
    atomicAdd(&C[(size_t)(m0 + rp) * 1024 + n0 + cp + 16], acc01 + bv1);
    atomicAdd(&C[(size_t)(m0 + rp + 16) * 1024 + n0 + cp], acc10 + bv0);
    atomicAdd(&C[(size_t)(m0 + rp + 16) * 1024 + n0 + cp + 16], acc11 + bv1);
}

// ---------------------------------------------------------------------------
// K1: blocks [0, B*S)     -> stage1 partials (32x32x16 bf16 MFMA, dbuf LDS)
//     blocks [B*S,+1024)  -> q-projection split-K partials into qa_ws
//
// stage1 per block: 64-slot chunks; each thread stages dims {2d2,2d2+1} x
// 8 slots as bf16 (b128 writes). Each wave owns a 32-row d-strip with 2-way
// k-split (waves kh=0/1 take slots [0,32)/[32,64) of each chunk), acc 2x16.
// LDS reads per chunk drop ~3.3x vs the 16x16 4-B-tile scheme -> HBM-bound.
// ---------------------------------------------------------------------------
__global__ __launch_bounds__(256, 4) void k1(const float* __restrict__ mem,
                                             const float* __restrict__ addr,
                                             float* __restrict__ pmat,
                                             float* __restrict__ pnorm,
                                             const float* __restrict__ query,
                                             const float* __restrict__ Wq,
                                             float* __restrict__ qa_ws,
                                             int S) {
    __shared__ __align__(16) char smem[38912];
    const int bid = blockIdx.x;
    const int nst = BATCH * S;

    if (bid >= nst) {
        const int b2 = bid - nst;
        const int m0 = (b2 & 3) * 32;
        const int n0 = ((b2 >> 2) & 31) * 32;
        const int ks = b2 >> 7;
        gemm_sk(query, Wq, nullptr, qa_ws, m0, n0, ks * 128, 4, (float*)smem);
        return;
    }

    float* norm_s = (float*)(smem + 36864);  // [8][64]

    const int t = threadIdx.x;
    const int g = t & 7;     // slot-group (8 slots)
    const int d2 = t >> 3;   // dim-pair: dims 2d2, 2d2+1
    const int l = t & 63;
    const int wv = t >> 6;
    const int strip = wv >> 1;  // d-strip 0/1
    const int kh = wv & 1;      // k-half within chunk
    const int lrow = l & 31;
    const int lh = l >> 5;

    const int b = bid & (BATCH - 1);
    const int s = bid >> 7;
    const int slots_per = NMEM / S;
    const int chunks = slots_per >> 6;

    const size_t mem_base = ((size_t)b * NMEM + (size_t)s * slots_per) * DMEM;
    const size_t addr_base = (size_t)s * slots_per * DMEM;
    const size_t toff = (size_t)(8 * g) * DMEM + 2 * d2;

    v16f acc0, acc1;
#pragma unroll
    for (int r = 0; r < 16; ++r) { acc0[r] = 0.f; acc1[r] = 0.f; }
    float nacc0 = 0.f, nacc1 = 0.f;

    v2f mr[8], ar[8];
#pragma unroll
    for (int j = 0; j < 8; ++j) {
        mr[j] = *(const v2f*)&mem[mem_base + toff + (size_t)j * DMEM];
        ar[j] = *(const v2f*)&addr[addr_base + toff + (size_t)j * DMEM];
    }

    for (int c = 0; c < chunks; ++c) {
        v8bf kv0, kv1, mv0, mv1;
#pragma unroll
        for (int j = 0; j < 8; ++j) {
            float k0 = fmaxf(mr[j][0] + ar[j][0], 0.f);
            float k1v = fmaxf(mr[j][1] + ar[j][1], 0.f);
            nacc0 += k0; nacc1 += k1v;
            kv0[j] = (__bf16)k0; kv1[j] = (__bf16)k1v;
            mv0[j] = (__bf16)mr[j][0]; mv1[j] = (__bf16)mr[j][1];
        }
        if (c + 1 < chunks) {  // prefetch next chunk
            const size_t coff = (size_t)(c + 1) * 64 * DMEM;
#pragma unroll
            for (int j = 0; j < 8; ++j) {
                mr[j] = *(const v2f*)&mem[mem_base + coff + toff + (size_t)j * DMEM];
                ar[j] = *(const v2f*)&addr[addr_base + coff + toff + (size_t)j * DMEM];
            }
        }
        __bf16* kb = (__bf16*)(smem + (c & 1) * 18432);
        __bf16* mb = kb + 64 * ROWB;
        *(v8bf*)&kb[(2 * d2) * ROWB + 8 * g] = kv0;
        *(v8bf*)&kb[(2 * d2 + 1) * ROWB + 8 * g] = kv1;
        *(v8bf*)&mb[(2 * d2) * ROWB + 8 * g] = mv0;
        *(v8bf*)&mb[(2 * d2 + 1) * ROWB + 8 * g] = mv1;
        __syncthreads();  // single barrier/iter: dbuf makes next write safe

        const int cb = 32 * kh + 8 * lh;
        v8bf a0 = *(v8bf*)&kb[(32 * strip + lrow) * ROWB + cb];
        v8bf a1 = *(v8bf*)&kb[(32 * strip + lrow) * ROWB + cb + 16];
        v8bf b00 = *(v8bf*)&mb[lrow * ROWB + cb];
        v8bf b01 = *(v8bf*)&mb[lrow * ROWB + cb + 16];
        v8bf b10 = *(v8bf*)&mb[(32 + lrow) * ROWB + cb];
        v8bf b11 = *(v8bf*)&mb[(32 + lrow) * ROWB + cb + 16];
        acc0 = __builtin_amdgcn_mfma_f32_32x32x16_bf16(a0, b00, acc0, 0, 0, 0);
        acc1 = __builtin_amdgcn_mfma_f32_32x32x16_bf16(a0, b10, acc1, 0, 0, 0);
        acc0 = __builtin_amdgcn_mfma_f32_32x32x16_bf16(a1, b01, acc0, 0, 0, 0);
        acc1 = __builtin_amdgcn_mfma_f32_32x32x16_bf16(a1, b11, acc1, 0, 0, 0);
    }

    __syncthreads();  // loop reads drained; reuse staging LDS for reduction
    float* red = (float*)smem;  // [2 strips][32 rows][64 e]
    norm_s[g * 64 + 2 * d2] = nacc0;
    norm_s[g * 64 + 2 * d2 + 1] = nacc1;
    if (kh == 1) {
#pragma unroll
        for (int r = 0; r < 16; ++r) {
            int row = (r & 3) + 8 * (r >> 2) + 4 * lh;
            red[strip * 2048 + row * 64 + lrow] = acc0[r];
            red[strip * 2048 + row * 64 + 32 + lrow] = acc1[r];
        }
    }
    __syncthreads();
    if (kh == 0) {
        float* pm = pmat + (size_t)bid * 4096;
#pragma unroll
        for (int r = 0; r < 16; ++r) {
            int row = (r & 3) + 8 * (r >> 2) + 4 * lh;
            int d = 32 * strip + row;
            pm[d * 64 + lrow] = acc0[r] + red[strip * 2048 + row * 64 + lrow];
            pm[d * 64 + 32 + lrow] = acc1[r] + red[strip * 2048 + row * 64 + 32 + lrow];
        }
    }
    if (t < 64) {
        float ssum = 0.f;
#pragma unroll
        for (int gg = 0; gg < 8; ++gg) ssum += norm_s[gg * 64 + t];
        pnorm[(size_t)bid * 64 + t] = ssum;
    }
}

// ---------------------------------------------------------------------------
// stage2: per batch, reduce S partials, finish qa = relu(q_raw + bq), then
// attn[h][e] = (qa[h]·matrix[:,e]) / (qa[h]·norm + 1e-5)
// ---------------------------------------------------------------------------
__global__ __launch_bounds__(256) void stage2(const float* __restrict__ pmat,
                                              const float* __restrict__ pnorm,
                                              const float* __restrict__ qa_raw,
                                              const float* __restrict__ bq,
                                              float* __restrict__ attn,
                                              int S) {
    __shared__ float mat_s[4096];
    __shared__ float qa_s[1024];
    __shared__ float nrm_s[64];
    const int t = threadIdx.x;
    const int b = blockIdx.x;

#pragma unroll
    for (int i = 0; i < 4; ++i) {
        const int vi = (t + 256 * i) * 4;
        v4f ssum = (v4f){0.f, 0.f, 0.f, 0.f};
        for (int s = 0; s < S; ++s) {
            v4f p = *(const v4f*)&pmat[((size_t)s * BATCH + b) * 4096 + vi];
            ssum += p;
        }
        *(v4f*)&mat_s[vi] = ssum;
    }
    if (t < 64) {
        float ssum = 0.f;
        for (int s = 0; s < S; ++s)
            ssum += pnorm[((size_t)s * BATCH + b) * 64 + t];
        nrm_s[t] = ssum;
    }
#pragma unroll
    for (int i = 0; i < 4; ++i) {
        const int idx = t + 256 * i;
        qa_s[idx] = fmaxf(qa_raw[(size_t)b * 1024 + idx] + bq[idx], 0.f);
    }
    __syncthreads();

    const int e = t & 63;
    const int hq = t >> 6;
#pragma unroll
    for (int i = 0; i < 4; ++i) {
        const int h = hq + 4 * i;
        float num = 0.f, den = 0.f;
#pragma unroll 8
        for (int d = 0; d < 64; ++d) {
            float q = qa_s[h * 64 + d];
            num = fmaf(q, mat_s[d * 64 + e], num);
            den = fmaf(q, nrm_s[d], den);
        }
        attn[(size_t)b * 1024 + h * 64 + e] = num / (den + 1e-5f);
    }
}

// ---------------------------------------------------------------------------
__global__ __launch_bounds__(256) void gemm_sk_kernel(const float* __restrict__ A,
                                                      const float* __restrict__ W,
                                                      const float* __restrict__ bias,
                                                      float* __restrict__ C) {
    __shared__ __align__(16) float smem[2 * 32 * 36];
    const int m0 = blockIdx.x * 32;
    const int n0 = blockIdx.y * 32;
    const int ks = blockIdx.z;
    gemm_sk(A, W, ks == 0 ? bias : nullptr, C, m0, n0, ks * 128, 4, smem);
}

// ---------------------------------------------------------------------------
extern "C" void kernel_launch(void* const* d_in, const int* in_sizes, int n_in,
                              void* d_out, int out_size, void* d_ws, size_t ws_size,
                              hipStream_t stream) {
    const float* query     = (const float*)d_in[0];
    const float* addresses = (const float*)d_in[1];
    const float* memories  = (const float*)d_in[2];
    const float* Wq        = (const float*)d_in[3];
    const float* bq        = (const float*)d_in[4];
    const float* Wm        = (const float*)d_in[5];
    const float* bm        = (const float*)d_in[6];
    float* out = (float*)d_out;
    float* ws = (float*)d_ws;

    int S = 8;
    while (S > 1) {
        size_t need = ((size_t)262144 + (size_t)S * (8192 + 524288)) * sizeof(float);
        if (need <= ws_size) break;
        S >>= 1;
    }

    float* qa_ws   = ws;                       // 131072 floats (raw partials)
    float* attn_ws = ws + 131072;              // 131072 floats
    float* pnorm   = ws + 262144;              // S*128*64 floats
    float* pmat    = pnorm + (size_t)S * 8192; // S*128*4096 floats

    hipMemsetAsync(qa_ws, 0, 131072 * sizeof(float), stream);
    hipMemsetAsync(out, 0, (size_t)out_size * sizeof(float), stream);

    k1<<<dim3(BATCH * S + 1024), 256, 0, stream>>>(memories, addresses, pmat,
                                                   pnorm, query, Wq, qa_ws, S);
    stage2<<<dim3(BATCH), 256, 0, stream>>>(pmat, pnorm, qa_ws, bq, attn_ws, S);
    gemm_sk_kernel<<<dim3(4, 32, 8), 256, 0, stream>>>(attn_ws, Wm, bm, out);
}

// Round 4
// 283.455 us; speedup vs baseline: 1.0723x; 1.0723x over previous
//
#include <hip/hip_runtime.h>
#include <hip/hip_bf16.h>

#define BATCH 128
#define DMEM 64
#define NMEM 4096
#define DMODEL 1024
#define LDS_STRIDE 40  // bf16 elems per dim-row (80 B): 16B-aligned b128 frags

typedef __bf16 v8bf __attribute__((ext_vector_type(8)));
typedef __bf16 v2bf __attribute__((ext_vector_type(2)));
typedef float v4f __attribute__((ext_vector_type(4)));
typedef float v16f __attribute__((ext_vector_type(16)));

// ---------------------------------------------------------------------------
// Split-K fp32 GEMM tile: C[m0+32][n0+32] += A[.][k0:k0+128] @ W^T
// atomicAdd accumulate; bias added by ks==0 blocks when non-null.
// ---------------------------------------------------------------------------
__global__ __launch_bounds__(256) void gemm_sk_kernel(const float* __restrict__ A,
                                                      const float* __restrict__ W,
                                                      const float* __restrict__ bias,
                                                      float* __restrict__ C) {
    __shared__ __align__(16) float smem[2 * 32 * 36];
    float(*As)[36] = (float(*)[36])smem;
    float(*Ws)[36] = (float(*)[36])(smem + 32 * 36);
    const int t = threadIdx.x;
    const int m0 = blockIdx.x * 32;
    const int n0 = blockIdx.y * 32;
    const int k0 = blockIdx.z * 128;
    const int lrow = t >> 3;
    const int lc4 = (t & 7) * 4;
    const int rp = t >> 4;
    const int cp = t & 15;

    float acc00 = 0.f, acc01 = 0.f, acc10 = 0.f, acc11 = 0.f;

    v4f av = *(const v4f*)&A[(size_t)(m0 + lrow) * DMODEL + k0 + lc4];
    v4f wv = *(const v4f*)&W[(size_t)(n0 + lrow) * DMODEL + k0 + lc4];

    for (int c = 0; c < 4; ++c) {
        __syncthreads();
        *(v4f*)&As[lrow][lc4] = av;
        *(v4f*)&Ws[lrow][lc4] = wv;
        __syncthreads();
        if (c + 1 < 4) {
            const int kc = k0 + (c + 1) * 32;
            av = *(const v4f*)&A[(size_t)(m0 + lrow) * DMODEL + kc + lc4];
            wv = *(const v4f*)&W[(size_t)(n0 + lrow) * DMODEL + kc + lc4];
        }
#pragma unroll
        for (int kk = 0; kk < 32; kk += 4) {
            v4f a0 = *(v4f*)&As[rp][kk];
            v4f a1 = *(v4f*)&As[rp + 16][kk];
            v4f b0 = *(v4f*)&Ws[cp][kk];
            v4f b1 = *(v4f*)&Ws[cp + 16][kk];
#pragma unroll
            for (int q = 0; q < 4; ++q) {
                acc00 = fmaf(a0[q], b0[q], acc00);
                acc01 = fmaf(a0[q], b1[q], acc01);
                acc10 = fmaf(a1[q], b0[q], acc10);
                acc11 = fmaf(a1[q], b1[q], acc11);
            }
        }
    }
    float bv0 = 0.f, bv1 = 0.f;
    if (bias && blockIdx.z == 0) { bv0 = bias[n0 + cp]; bv1 = bias[n0 + cp + 16]; }
    atomicAdd(&C[(size_t)(m0 + rp) * 1024 + n0 + cp], acc00 + bv0);
    atomicAdd(&C[(size_t)(m0 + rp) * 1024 + n0 + cp + 16], acc01 + bv1);
    atomicAdd(&C[(size_t)(m0 + rp + 16) * 1024 + n0 + cp], acc10 + bv0);
    atomicAdd(&C[(size_t)(m0 + rp + 16) * 1024 + n0 + cp + 16], acc11 + bv1);
}

// ---------------------------------------------------------------------------
// stage1: per (b,s) block, 32-slot chunks. Staging = round-2's proven map:
// thread (u=t&15, v=t>>4) reads dims [4u,4u+4) of slots {2v,2v+1} as v4f
// (coalesced 1KB/16 lanes), packs bf16 pairs into dim-major LDS (b32 writes).
// Compute = 32x32x16 MFMA (r3-verified mapping), 4 waves = 2 d-strips x
// 2-way k-split; acc 2x v16f. LDS double-buffered, one barrier per chunk.
// ---------------------------------------------------------------------------
__global__ __launch_bounds__(256, 4) void stage1(const float* __restrict__ mem,
                                                 const float* __restrict__ addr,
                                                 float* __restrict__ pmat,
                                                 float* __restrict__ pnorm,
                                                 int S) {
    __shared__ __align__(16) char smem[24576];
    float* norm_s = (float*)(smem + 20480);  // [16][64] floats

    const int t = threadIdx.x;
    const int bid = blockIdx.x;
    const int b = bid & (BATCH - 1);
    const int s = bid >> 7;
    const int slots_per = NMEM / S;
    const int chunks = slots_per >> 5;

    const int u = t & 15;
    const int v = t >> 4;
    const int d0 = u * 4;

    const int l = t & 63;
    const int wv = t >> 6;
    const int strip = wv >> 1;
    const int kh = wv & 1;
    const int lrow = l & 31;
    const int lh = l >> 5;

    const size_t mem_base = ((size_t)b * NMEM + (size_t)s * slots_per) * DMEM;
    const size_t addr_base = (size_t)s * slots_per * DMEM;
    const size_t so = (size_t)(2 * v) * DMEM + d0;

    v16f acc0, acc1;
#pragma unroll
    for (int r = 0; r < 16; ++r) { acc0[r] = 0.f; acc1[r] = 0.f; }
    float nacc[4] = {0.f, 0.f, 0.f, 0.f};

    v4f m0v = *(const v4f*)&mem[mem_base + so];
    v4f m1v = *(const v4f*)&mem[mem_base + so + DMEM];
    v4f a0v = *(const v4f*)&addr[addr_base + so];
    v4f a1v = *(const v4f*)&addr[addr_base + so + DMEM];

    for (int c = 0; c < chunks; ++c) {
        __bf16* kb = (__bf16*)(smem + (c & 1) * 10240);
        __bf16* mb = kb + 64 * LDS_STRIDE;
#pragma unroll
        for (int i = 0; i < 4; ++i) {
            float kf0 = fmaxf(m0v[i] + a0v[i], 0.f);
            float kf1 = fmaxf(m1v[i] + a1v[i], 0.f);
            nacc[i] += kf0 + kf1;
            v2bf kp; kp[0] = (__bf16)kf0; kp[1] = (__bf16)kf1;
            v2bf mp; mp[0] = (__bf16)m0v[i]; mp[1] = (__bf16)m1v[i];
            *(v2bf*)&kb[(d0 + i) * LDS_STRIDE + 2 * v] = kp;
            *(v2bf*)&mb[(d0 + i) * LDS_STRIDE + 2 * v] = mp;
        }
        if (c + 1 < chunks) {  // prefetch next chunk (coalesced v4f)
            const size_t coff = (size_t)(c + 1) * 32 * DMEM;
            m0v = *(const v4f*)&mem[mem_base + coff + so];
            m1v = *(const v4f*)&mem[mem_base + coff + so + DMEM];
            a0v = *(const v4f*)&addr[addr_base + coff + so];
            a1v = *(const v4f*)&addr[addr_base + coff + so + DMEM];
        }
        __syncthreads();  // dbuf: single barrier between write & frag read

        const int cb = 16 * kh + 8 * lh;
        v8bf af = *(v8bf*)&kb[(32 * strip + lrow) * LDS_STRIDE + cb];
        v8bf b0 = *(v8bf*)&mb[lrow * LDS_STRIDE + cb];
        v8bf b1 = *(v8bf*)&mb[(32 + lrow) * LDS_STRIDE + cb];
        acc0 = __builtin_amdgcn_mfma_f32_32x32x16_bf16(af, b0, acc0, 0, 0, 0);
        acc1 = __builtin_amdgcn_mfma_f32_32x32x16_bf16(af, b1, acc1, 0, 0, 0);
    }

    __syncthreads();  // drain frag reads; reuse staging LDS as reduce buffer
    float* red = (float*)smem;  // [2 strips][32 rows][64 e] = 16 KB
#pragma unroll
    for (int i = 0; i < 4; ++i) norm_s[v * 64 + d0 + i] = nacc[i];
    if (kh == 1) {
#pragma unroll
        for (int r = 0; r < 16; ++r) {
            int row = (r & 3) + 8 * (r >> 2) + 4 * lh;
            red[strip * 2048 + row * 64 + lrow] = acc0[r];
            red[strip * 2048 + row * 64 + 32 + lrow] = acc1[r];
        }
    }
    __syncthreads();
    if (kh == 0) {
        float* pm = pmat + (size_t)bid * 4096;
#pragma unroll
        for (int r = 0; r < 16; ++r) {
            int row = (r & 3) + 8 * (r >> 2) + 4 * lh;
            int d = 32 * strip + row;
            pm[d * 64 + lrow] = acc0[r] + red[strip * 2048 + row * 64 + lrow];
            pm[d * 64 + 32 + lrow] = acc1[r] + red[strip * 2048 + row * 64 + 32 + lrow];
        }
    }
    if (t < 64) {
        float ssum = 0.f;
#pragma unroll
        for (int g = 0; g < 16; ++g) ssum += norm_s[g * 64 + t];
        pnorm[(size_t)bid * 64 + t] = ssum;
    }
}

// ---------------------------------------------------------------------------
// stage2: per batch, reduce S partials, finish qa = relu(q_raw + bq), then
// attn[h][e] = (qa[h]·matrix[:,e]) / (qa[h]·norm + 1e-5)
// ---------------------------------------------------------------------------
__global__ __launch_bounds__(256) void stage2(const float* __restrict__ pmat,
                                              const float* __restrict__ pnorm,
                                              const float* __restrict__ qa_raw,
                                              const float* __restrict__ bq,
                                              float* __restrict__ attn,
                                              int S) {
    __shared__ float mat_s[4096];
    __shared__ float qa_s[1024];
    __shared__ float nrm_s[64];
    const int t = threadIdx.x;
    const int b = blockIdx.x;

#pragma unroll
    for (int i = 0; i < 4; ++i) {
        const int vi = (t + 256 * i) * 4;
        v4f ssum = (v4f){0.f, 0.f, 0.f, 0.f};
        for (int s = 0; s < S; ++s) {
            v4f p = *(const v4f*)&pmat[((size_t)s * BATCH + b) * 4096 + vi];
            ssum += p;
        }
        *(v4f*)&mat_s[vi] = ssum;
    }
    if (t < 64) {
        float ssum = 0.f;
        for (int s = 0; s < S; ++s)
            ssum += pnorm[((size_t)s * BATCH + b) * 64 + t];
        nrm_s[t] = ssum;
    }
#pragma unroll
    for (int i = 0; i < 4; ++i) {
        const int idx = t + 256 * i;
        qa_s[idx] = fmaxf(qa_raw[(size_t)b * 1024 + idx] + bq[idx], 0.f);
    }
    __syncthreads();

    const int e = t & 63;
    const int hq = t >> 6;
#pragma unroll
    for (int i = 0; i < 4; ++i) {
        const int h = hq + 4 * i;
        float num = 0.f, den = 0.f;
#pragma unroll 8
        for (int d = 0; d < 64; ++d) {
            float q = qa_s[h * 64 + d];
            num = fmaf(q, mat_s[d * 64 + e], num);
            den = fmaf(q, nrm_s[d], den);
        }
        attn[(size_t)b * 1024 + h * 64 + e] = num / (den + 1e-5f);
    }
}

// ---------------------------------------------------------------------------
extern "C" void kernel_launch(void* const* d_in, const int* in_sizes, int n_in,
                              void* d_out, int out_size, void* d_ws, size_t ws_size,
                              hipStream_t stream) {
    const float* query     = (const float*)d_in[0];
    const float* addresses = (const float*)d_in[1];
    const float* memories  = (const float*)d_in[2];
    const float* Wq        = (const float*)d_in[3];
    const float* bq        = (const float*)d_in[4];
    const float* Wm        = (const float*)d_in[5];
    const float* bm        = (const float*)d_in[6];
    float* out = (float*)d_out;
    float* ws = (float*)d_ws;

    int S = 8;
    while (S > 1) {
        size_t need = ((size_t)262144 + (size_t)S * (8192 + 524288)) * sizeof(float);
        if (need <= ws_size) break;
        S >>= 1;
    }

    float* qa_ws   = ws;                       // 131072 floats (raw partials)
    float* attn_ws = ws + 131072;              // 131072 floats
    float* pnorm   = ws + 262144;              // S*128*64 floats
    float* pmat    = pnorm + (size_t)S * 8192; // S*128*4096 floats

    hipMemsetAsync(qa_ws, 0, 131072 * sizeof(float), stream);
    hipMemsetAsync(out, 0, (size_t)out_size * sizeof(float), stream);

    gemm_sk_kernel<<<dim3(4, 32, 8), 256, 0, stream>>>(query, Wq, nullptr, qa_ws);
    stage1<<<dim3(BATCH * S), 256, 0, stream>>>(memories, addresses, pmat, pnorm, S);
    stage2<<<dim3(BATCH), 256, 0, stream>>>(pmat, pnorm, qa_ws, bq, attn_ws, S);
    gemm_sk_kernel<<<dim3(4, 32, 8), 256, 0, stream>>>(attn_ws, Wm, bm, out);
}

// Round 5
// 260.616 us; speedup vs baseline: 1.1663x; 1.0876x over previous
//
#include <hip/hip_runtime.h>
#include <hip/hip_bf16.h>

#define BATCH 128
#define DMEM 64
#define NMEM 4096
#define DMODEL 1024
#define LDS_STRIDE 40  // bf16 elems per dim-row (80 B): 16B-aligned b128 frags

typedef __bf16 v8bf __attribute__((ext_vector_type(8)));
typedef __bf16 v2bf __attribute__((ext_vector_type(2)));
typedef float v4f __attribute__((ext_vector_type(4)));
typedef float v16f __attribute__((ext_vector_type(16)));

// ---------------------------------------------------------------------------
// Split-K fp32 GEMM tile body: C[m0+32][n0+32] += A[.][k0:k0+128] @ W^T
// atomicAdd accumulate; bias added when non-null (ks==0 caller passes it).
// ---------------------------------------------------------------------------
__device__ __forceinline__ void gemm_sk(const float* __restrict__ A,
                                        const float* __restrict__ W,
                                        const float* __restrict__ bias,
                                        float* __restrict__ C,
                                        int m0, int n0, int k0,
                                        float* smem) {
    float(*As)[36] = (float(*)[36])smem;
    float(*Ws)[36] = (float(*)[36])(smem + 32 * 36);
    const int t = threadIdx.x;
    const int lrow = t >> 3;
    const int lc4 = (t & 7) * 4;
    const int rp = t >> 4;
    const int cp = t & 15;

    float acc00 = 0.f, acc01 = 0.f, acc10 = 0.f, acc11 = 0.f;

    v4f av = *(const v4f*)&A[(size_t)(m0 + lrow) * DMODEL + k0 + lc4];
    v4f wv = *(const v4f*)&W[(size_t)(n0 + lrow) * DMODEL + k0 + lc4];

    for (int c = 0; c < 4; ++c) {
        __syncthreads();
        *(v4f*)&As[lrow][lc4] = av;
        *(v4f*)&Ws[lrow][lc4] = wv;
        __syncthreads();
        if (c + 1 < 4) {
            const int kc = k0 + (c + 1) * 32;
            av = *(const v4f*)&A[(size_t)(m0 + lrow) * DMODEL + kc + lc4];
            wv = *(const v4f*)&W[(size_t)(n0 + lrow) * DMODEL + kc + lc4];
        }
#pragma unroll
        for (int kk = 0; kk < 32; kk += 4) {
            v4f a0 = *(v4f*)&As[rp][kk];
            v4f a1 = *(v4f*)&As[rp + 16][kk];
            v4f b0 = *(v4f*)&Ws[cp][kk];
            v4f b1 = *(v4f*)&Ws[cp + 16][kk];
#pragma unroll
            for (int q = 0; q < 4; ++q) {
                acc00 = fmaf(a0[q], b0[q], acc00);
                acc01 = fmaf(a0[q], b1[q], acc01);
                acc10 = fmaf(a1[q], b0[q], acc10);
                acc11 = fmaf(a1[q], b1[q], acc11);
            }
        }
    }
    float bv0 = 0.f, bv1 = 0.f;
    if (bias) { bv0 = bias[n0 + cp]; bv1 = bias[n0 + cp + 16]; }
    atomicAdd(&C[(size_t)(m0 + rp) * 1024 + n0 + cp], acc00 + bv0);
    atomicAdd(&C[(size_t)(m0 + rp) * 1024 + n0 + cp + 16], acc01 + bv1);
    atomicAdd(&C[(size_t)(m0 + rp + 16) * 1024 + n0 + cp], acc10 + bv0);
    atomicAdd(&C[(size_t)(m0 + rp + 16) * 1024 + n0 + cp + 16], acc11 + bv1);
}

// ---------------------------------------------------------------------------
// K1: blocks [0, B*S)    -> stage1 partials (32x32x16 bf16 MFMA, dbuf LDS,
//                           2-chunk-deep register prefetch)
//     blocks [B*S,+1024) -> q-projection split-K partials into qa_ws
// ---------------------------------------------------------------------------
__global__ __launch_bounds__(256, 4) void k1(const float* __restrict__ mem,
                                             const float* __restrict__ addr,
                                             float* __restrict__ pmat,
                                             float* __restrict__ pnorm,
                                             const float* __restrict__ query,
                                             const float* __restrict__ Wq,
                                             float* __restrict__ qa_ws,
                                             int S) {
    __shared__ __align__(16) char smem[24576];
    const int bid = blockIdx.x;
    const int nst = BATCH * S;

    if (bid >= nst) {
        const int b2 = bid - nst;
        const int m0 = (b2 & 3) * 32;
        const int n0 = ((b2 >> 2) & 31) * 32;
        const int ks = b2 >> 7;
        gemm_sk(query, Wq, nullptr, qa_ws, m0, n0, ks * 128, (float*)smem);
        return;
    }

    float* norm_s = (float*)(smem + 20480);  // [16][64] floats

    const int t = threadIdx.x;
    const int b = bid & (BATCH - 1);
    const int s = bid >> 7;
    const int slots_per = NMEM / S;
    const int chunks = slots_per >> 5;  // even for all S used

    const int u = t & 15;
    const int v = t >> 4;
    const int d0 = u * 4;

    const int l = t & 63;
    const int wv = t >> 6;
    const int strip = wv >> 1;
    const int kh = wv & 1;
    const int lrow = l & 31;
    const int lh = l >> 5;

    const size_t mem_base = ((size_t)b * NMEM + (size_t)s * slots_per) * DMEM;
    const size_t addr_base = (size_t)s * slots_per * DMEM;
    const size_t so = (size_t)(2 * v) * DMEM + d0;

    v16f acc0, acc1;
#pragma unroll
    for (int r = 0; r < 16; ++r) { acc0[r] = 0.f; acc1[r] = 0.f; }
    float nacc[4] = {0.f, 0.f, 0.f, 0.f};

    // even/odd register sets -> prefetch distance of 2 chunks, no reg moves
    v4f mE0 = *(const v4f*)&mem[mem_base + so];
    v4f mE1 = *(const v4f*)&mem[mem_base + so + DMEM];
    v4f aE0 = *(const v4f*)&addr[addr_base + so];
    v4f aE1 = *(const v4f*)&addr[addr_base + so + DMEM];
    v4f mO0 = *(const v4f*)&mem[mem_base + 2048 + so];
    v4f mO1 = *(const v4f*)&mem[mem_base + 2048 + so + DMEM];
    v4f aO0 = *(const v4f*)&addr[addr_base + 2048 + so];
    v4f aO1 = *(const v4f*)&addr[addr_base + 2048 + so + DMEM];

    __bf16* kb0 = (__bf16*)smem;
    __bf16* mb0 = kb0 + 64 * LDS_STRIDE;
    __bf16* kb1 = (__bf16*)(smem + 10240);
    __bf16* mb1 = kb1 + 64 * LDS_STRIDE;
    const int cb = 16 * kh + 8 * lh;

    for (int cc = 0; cc < chunks; cc += 2) {
        // ---- even chunk ----
#pragma unroll
        for (int i = 0; i < 4; ++i) {
            float kf0 = fmaxf(mE0[i] + aE0[i], 0.f);
            float kf1 = fmaxf(mE1[i] + aE1[i], 0.f);
            nacc[i] += kf0 + kf1;
            v2bf kp; kp[0] = (__bf16)kf0; kp[1] = (__bf16)kf1;
            v2bf mp; mp[0] = (__bf16)mE0[i]; mp[1] = (__bf16)mE1[i];
            *(v2bf*)&kb0[(d0 + i) * LDS_STRIDE + 2 * v] = kp;
            *(v2bf*)&mb0[(d0 + i) * LDS_STRIDE + 2 * v] = mp;
        }
        if (cc + 2 < chunks) {
            const size_t coff = (size_t)(cc + 2) * 32 * DMEM;
            mE0 = *(const v4f*)&mem[mem_base + coff + so];
            mE1 = *(const v4f*)&mem[mem_base + coff + so + DMEM];
            aE0 = *(const v4f*)&addr[addr_base + coff + so];
            aE1 = *(const v4f*)&addr[addr_base + coff + so + DMEM];
        }
        __syncthreads();
        {
            v8bf af = *(v8bf*)&kb0[(32 * strip + lrow) * LDS_STRIDE + cb];
            v8bf b0 = *(v8bf*)&mb0[lrow * LDS_STRIDE + cb];
            v8bf b1 = *(v8bf*)&mb0[(32 + lrow) * LDS_STRIDE + cb];
            acc0 = __builtin_amdgcn_mfma_f32_32x32x16_bf16(af, b0, acc0, 0, 0, 0);
            acc1 = __builtin_amdgcn_mfma_f32_32x32x16_bf16(af, b1, acc1, 0, 0, 0);
        }
        // ---- odd chunk ----
#pragma unroll
        for (int i = 0; i < 4; ++i) {
            float kf0 = fmaxf(mO0[i] + aO0[i], 0.f);
            float kf1 = fmaxf(mO1[i] + aO1[i], 0.f);
            nacc[i] += kf0 + kf1;
            v2bf kp; kp[0] = (__bf16)kf0; kp[1] = (__bf16)kf1;
            v2bf mp; mp[0] = (__bf16)mO0[i]; mp[1] = (__bf16)mO1[i];
            *(v2bf*)&kb1[(d0 + i) * LDS_STRIDE + 2 * v] = kp;
            *(v2bf*)&mb1[(d0 + i) * LDS_STRIDE + 2 * v] = mp;
        }
        if (cc + 3 < chunks) {
            const size_t coff = (size_t)(cc + 3) * 32 * DMEM;
            mO0 = *(const v4f*)&mem[mem_base + coff + so];
            mO1 = *(const v4f*)&mem[mem_base + coff + so + DMEM];
            aO0 = *(const v4f*)&addr[addr_base + coff + so];
            aO1 = *(const v4f*)&addr[addr_base + coff + so + DMEM];
        }
        __syncthreads();
        {
            v8bf af = *(v8bf*)&kb1[(32 * strip + lrow) * LDS_STRIDE + cb];
            v8bf b0 = *(v8bf*)&mb1[lrow * LDS_STRIDE + cb];
            v8bf b1 = *(v8bf*)&mb1[(32 + lrow) * LDS_STRIDE + cb];
            acc0 = __builtin_amdgcn_mfma_f32_32x32x16_bf16(af, b0, acc0, 0, 0, 0);
            acc1 = __builtin_amdgcn_mfma_f32_32x32x16_bf16(af, b1, acc1, 0, 0, 0);
        }
    }

    __syncthreads();  // drain frag reads; reuse staging LDS as reduce buffer
    float* red = (float*)smem;  // [2 strips][32 rows][64 e] = 16 KB
#pragma unroll
    for (int i = 0; i < 4; ++i) norm_s[v * 64 + d0 + i] = nacc[i];
    if (kh == 1) {
#pragma unroll
        for (int r = 0; r < 16; ++r) {
            int row = (r & 3) + 8 * (r >> 2) + 4 * lh;
            red[strip * 2048 + row * 64 + lrow] = acc0[r];
            red[strip * 2048 + row * 64 + 32 + lrow] = acc1[r];
        }
    }
    __syncthreads();
    if (kh == 0) {
        float* pm = pmat + (size_t)bid * 4096;
#pragma unroll
        for (int r = 0; r < 16; ++r) {
            int row = (r & 3) + 8 * (r >> 2) + 4 * lh;
            int d = 32 * strip + row;
            pm[d * 64 + lrow] = acc0[r] + red[strip * 2048 + row * 64 + lrow];
            pm[d * 64 + 32 + lrow] = acc1[r] + red[strip * 2048 + row * 64 + 32 + lrow];
        }
    }
    if (t < 64) {
        float ssum = 0.f;
#pragma unroll
        for (int g = 0; g < 16; ++g) ssum += norm_s[g * 64 + t];
        pnorm[(size_t)bid * 64 + t] = ssum;
    }
}

// ---------------------------------------------------------------------------
// stage2: per batch, reduce S partials, finish qa = relu(q_raw + bq), then
// attn[h][e] = (qa[h]·matrix[:,e]) / (qa[h]·norm + 1e-5)
// ---------------------------------------------------------------------------
__global__ __launch_bounds__(256) void stage2(const float* __restrict__ pmat,
                                              const float* __restrict__ pnorm,
                                              const float* __restrict__ qa_raw,
                                              const float* __restrict__ bq,
                                              float* __restrict__ attn,
                                              int S) {
    __shared__ float mat_s[4096];
    __shared__ float qa_s[1024];
    __shared__ float nrm_s[64];
    const int t = threadIdx.x;
    const int b = blockIdx.x;

#pragma unroll
    for (int i = 0; i < 4; ++i) {
        const int vi = (t + 256 * i) * 4;
        v4f ssum = (v4f){0.f, 0.f, 0.f, 0.f};
        for (int s = 0; s < S; ++s) {
            v4f p = *(const v4f*)&pmat[((size_t)s * BATCH + b) * 4096 + vi];
            ssum += p;
        }
        *(v4f*)&mat_s[vi] = ssum;
    }
    if (t < 64) {
        float ssum = 0.f;
        for (int s = 0; s < S; ++s)
            ssum += pnorm[((size_t)s * BATCH + b) * 64 + t];
        nrm_s[t] = ssum;
    }
#pragma unroll
    for (int i = 0; i < 4; ++i) {
        const int idx = t + 256 * i;
        qa_s[idx] = fmaxf(qa_raw[(size_t)b * 1024 + idx] + bq[idx], 0.f);
    }
    __syncthreads();

    const int e = t & 63;
    const int hq = t >> 6;
#pragma unroll
    for (int i = 0; i < 4; ++i) {
        const int h = hq + 4 * i;
        float num = 0.f, den = 0.f;
#pragma unroll 8
        for (int d = 0; d < 64; ++d) {
            float q = qa_s[h * 64 + d];
            num = fmaf(q, mat_s[d * 64 + e], num);
            den = fmaf(q, nrm_s[d], den);
        }
        attn[(size_t)b * 1024 + h * 64 + e] = num / (den + 1e-5f);
    }
}

// ---------------------------------------------------------------------------
__global__ __launch_bounds__(256) void gemm_sk_kernel(const float* __restrict__ A,
                                                      const float* __restrict__ W,
                                                      const float* __restrict__ bias,
                                                      float* __restrict__ C) {
    __shared__ __align__(16) float smem[2 * 32 * 36];
    const int m0 = blockIdx.x * 32;
    const int n0 = blockIdx.y * 32;
    const int ks = blockIdx.z;
    gemm_sk(A, W, ks == 0 ? bias : nullptr, C, m0, n0, ks * 128, smem);
}

// ---------------------------------------------------------------------------
extern "C" void kernel_launch(void* const* d_in, const int* in_sizes, int n_in,
                              void* d_out, int out_size, void* d_ws, size_t ws_size,
                              hipStream_t stream) {
    const float* query     = (const float*)d_in[0];
    const float* addresses = (const float*)d_in[1];
    const float* memories  = (const float*)d_in[2];
    const float* Wq        = (const float*)d_in[3];
    const float* bq        = (const float*)d_in[4];
    const float* Wm        = (const float*)d_in[5];
    const float* bm        = (const float*)d_in[6];
    float* out = (float*)d_out;
    float* ws = (float*)d_ws;

    int S = 8;
    while (S > 1) {
        size_t need = ((size_t)262144 + (size_t)S * (8192 + 524288)) * sizeof(float);
        if (need <= ws_size) break;
        S >>= 1;
    }

    float* qa_ws   = ws;                       // 131072 floats (raw partials)
    float* attn_ws = ws + 131072;              // 131072 floats
    float* pnorm   = ws + 262144;              // S*128*64 floats
    float* pmat    = pnorm + (size_t)S * 8192; // S*128*4096 floats

    hipMemsetAsync(qa_ws, 0, 131072 * sizeof(float), stream);
    hipMemsetAsync(out, 0, (size_t)out_size * sizeof(float), stream);

    k1<<<dim3(BATCH * S + 1024), 256, 0, stream>>>(memories, addresses, pmat,
                                                   pnorm, query, Wq, qa_ws, S);
    stage2<<<dim3(BATCH), 256, 0, stream>>>(pmat, pnorm, qa_ws, bq, attn_ws, S);
    gemm_sk_kernel<<<dim3(4, 32, 8), 256, 0, stream>>>(attn_ws, Wm, bm, out);
}

// Round 6
// 226.797 us; speedup vs baseline: 1.3402x; 1.1491x over previous
//
#include <hip/hip_runtime.h>
#include <hip/hip_bf16.h>

#define BATCH 128
#define DMEM 64
#define NMEM 4096
#define DMODEL 1024
#define S1 4            // stage1 N-splits
#define LDS_STRIDE 40   // bf16 elems per dim-row (80 B)

typedef __bf16 v8bf __attribute__((ext_vector_type(8)));
typedef __bf16 v2bf __attribute__((ext_vector_type(2)));
typedef float v4f __attribute__((ext_vector_type(4)));
typedef float v16f __attribute__((ext_vector_type(16)));

// ---------------------------------------------------------------------------
// Split-K fp32 GEMM tile body: dst[m0+32][n0+32] = A[.][k0:k0+128] @ W^T
// Plain stores (each (ks,row,col) written exactly once).
// ---------------------------------------------------------------------------
__device__ __forceinline__ void gemm_sk(const float* __restrict__ A,
                                        const float* __restrict__ W,
                                        float* __restrict__ dst,
                                        int m0, int n0, int k0,
                                        float* smem) {
    float(*As)[36] = (float(*)[36])smem;
    float(*Ws)[36] = (float(*)[36])(smem + 32 * 36);
    const int t = threadIdx.x;
    const int lrow = t >> 3;
    const int lc4 = (t & 7) * 4;
    const int rp = t >> 4;
    const int cp = t & 15;

    float acc00 = 0.f, acc01 = 0.f, acc10 = 0.f, acc11 = 0.f;

    v4f av = *(const v4f*)&A[(size_t)(m0 + lrow) * DMODEL + k0 + lc4];
    v4f wv = *(const v4f*)&W[(size_t)(n0 + lrow) * DMODEL + k0 + lc4];

    for (int c = 0; c < 4; ++c) {
        __syncthreads();
        *(v4f*)&As[lrow][lc4] = av;
        *(v4f*)&Ws[lrow][lc4] = wv;
        __syncthreads();
        if (c + 1 < 4) {
            const int kc = k0 + (c + 1) * 32;
            av = *(const v4f*)&A[(size_t)(m0 + lrow) * DMODEL + kc + lc4];
            wv = *(const v4f*)&W[(size_t)(n0 + lrow) * DMODEL + kc + lc4];
        }
#pragma unroll
        for (int kk = 0; kk < 32; kk += 4) {
            v4f a0 = *(v4f*)&As[rp][kk];
            v4f a1 = *(v4f*)&As[rp + 16][kk];
            v4f b0 = *(v4f*)&Ws[cp][kk];
            v4f b1 = *(v4f*)&Ws[cp + 16][kk];
#pragma unroll
            for (int q = 0; q < 4; ++q) {
                acc00 = fmaf(a0[q], b0[q], acc00);
                acc01 = fmaf(a0[q], b1[q], acc01);
                acc10 = fmaf(a1[q], b0[q], acc10);
                acc11 = fmaf(a1[q], b1[q], acc11);
            }
        }
    }
    dst[(size_t)(m0 + rp) * DMODEL + n0 + cp] = acc00;
    dst[(size_t)(m0 + rp) * DMODEL + n0 + cp + 16] = acc01;
    dst[(size_t)(m0 + rp + 16) * DMODEL + n0 + cp] = acc10;
    dst[(size_t)(m0 + rp + 16) * DMODEL + n0 + cp + 16] = acc11;
}

// ---------------------------------------------------------------------------
// K1: blocks [0,512)      -> stage1 partials (32x32x16 bf16 MFMA, dbuf LDS,
//                            depth-2 register prefetch); S1=4 splits
//     blocks [512,+1024)  -> q-projection split-K(8) partials into qa_p
// stage1 output pmat is TRANSPOSED: pmat[s][b][e][d] (rows contiguous in d)
// ---------------------------------------------------------------------------
__global__ __launch_bounds__(256, 3) void k1(const float* __restrict__ mem,
                                             const float* __restrict__ addr,
                                             float* __restrict__ pmat,
                                             float* __restrict__ pnorm,
                                             const float* __restrict__ query,
                                             const float* __restrict__ Wq,
                                             float* __restrict__ qa_p) {
    __shared__ __align__(16) char smem[24576];
    const int bid = blockIdx.x;
    const int nst = BATCH * S1;  // 512

    if (bid >= nst) {
        const int b2 = bid - nst;            // 0..1023
        const int m0 = (b2 & 3) * 32;
        const int n0 = ((b2 >> 2) & 31) * 32;
        const int ks = b2 >> 7;              // 0..7
        gemm_sk(query, Wq, qa_p + (size_t)ks * BATCH * DMODEL,
                m0, n0, ks * 128, (float*)smem);
        return;
    }

    float* norm_s = (float*)(smem + 20480);  // [16][64] floats

    const int t = threadIdx.x;
    const int b = bid & (BATCH - 1);
    const int s = bid >> 7;                  // 0..3
    const int slots_per = NMEM / S1;         // 1024
    const int chunks = slots_per >> 5;       // 32

    const int u = t & 15;
    const int v = t >> 4;
    const int d0 = u * 4;

    const int l = t & 63;
    const int wv = t >> 6;
    const int strip = wv >> 1;
    const int kh = wv & 1;
    const int lrow = l & 31;
    const int lh = l >> 5;

    const size_t mem_base = ((size_t)b * NMEM + (size_t)s * slots_per) * DMEM;
    const size_t addr_base = (size_t)s * slots_per * DMEM;
    const size_t so = (size_t)(2 * v) * DMEM + d0;

    v16f acc0, acc1;
#pragma unroll
    for (int r = 0; r < 16; ++r) { acc0[r] = 0.f; acc1[r] = 0.f; }
    float nacc[4] = {0.f, 0.f, 0.f, 0.f};

    // even/odd register sets -> prefetch distance of 2 chunks
    v4f mE0 = *(const v4f*)&mem[mem_base + so];
    v4f mE1 = *(const v4f*)&mem[mem_base + so + DMEM];
    v4f aE0 = *(const v4f*)&addr[addr_base + so];
    v4f aE1 = *(const v4f*)&addr[addr_base + so + DMEM];
    v4f mO0 = *(const v4f*)&mem[mem_base + 2048 + so];
    v4f mO1 = *(const v4f*)&mem[mem_base + 2048 + so + DMEM];
    v4f aO0 = *(const v4f*)&addr[addr_base + 2048 + so];
    v4f aO1 = *(const v4f*)&addr[addr_base + 2048 + so + DMEM];

    __bf16* kb0 = (__bf16*)smem;
    __bf16* mb0 = kb0 + 64 * LDS_STRIDE;
    __bf16* kb1 = (__bf16*)(smem + 10240);
    __bf16* mb1 = kb1 + 64 * LDS_STRIDE;
    const int cb = 16 * kh + 8 * lh;

    for (int cc = 0; cc < chunks; cc += 2) {
        // ---- even chunk ----
#pragma unroll
        for (int i = 0; i < 4; ++i) {
            float kf0 = fmaxf(mE0[i] + aE0[i], 0.f);
            float kf1 = fmaxf(mE1[i] + aE1[i], 0.f);
            nacc[i] += kf0 + kf1;
            v2bf kp; kp[0] = (__bf16)kf0; kp[1] = (__bf16)kf1;
            v2bf mp; mp[0] = (__bf16)mE0[i]; mp[1] = (__bf16)mE1[i];
            *(v2bf*)&kb0[(d0 + i) * LDS_STRIDE + 2 * v] = kp;
            *(v2bf*)&mb0[(d0 + i) * LDS_STRIDE + 2 * v] = mp;
        }
        if (cc + 2 < chunks) {
            const size_t coff = (size_t)(cc + 2) * 32 * DMEM;
            mE0 = *(const v4f*)&mem[mem_base + coff + so];
            mE1 = *(const v4f*)&mem[mem_base + coff + so + DMEM];
            aE0 = *(const v4f*)&addr[addr_base + coff + so];
            aE1 = *(const v4f*)&addr[addr_base + coff + so + DMEM];
        }
        __syncthreads();
        {
            v8bf af = *(v8bf*)&kb0[(32 * strip + lrow) * LDS_STRIDE + cb];
            v8bf b0 = *(v8bf*)&mb0[lrow * LDS_STRIDE + cb];
            v8bf b1 = *(v8bf*)&mb0[(32 + lrow) * LDS_STRIDE + cb];
            acc0 = __builtin_amdgcn_mfma_f32_32x32x16_bf16(af, b0, acc0, 0, 0, 0);
            acc1 = __builtin_amdgcn_mfma_f32_32x32x16_bf16(af, b1, acc1, 0, 0, 0);
        }
        // ---- odd chunk ----
#pragma unroll
        for (int i = 0; i < 4; ++i) {
            float kf0 = fmaxf(mO0[i] + aO0[i], 0.f);
            float kf1 = fmaxf(mO1[i] + aO1[i], 0.f);
            nacc[i] += kf0 + kf1;
            v2bf kp; kp[0] = (__bf16)kf0; kp[1] = (__bf16)kf1;
            v2bf mp; mp[0] = (__bf16)mO0[i]; mp[1] = (__bf16)mO1[i];
            *(v2bf*)&kb1[(d0 + i) * LDS_STRIDE + 2 * v] = kp;
            *(v2bf*)&mb1[(d0 + i) * LDS_STRIDE + 2 * v] = mp;
        }
        if (cc + 3 < chunks) {
            const size_t coff = (size_t)(cc + 3) * 32 * DMEM;
            mO0 = *(const v4f*)&mem[mem_base + coff + so];
            mO1 = *(const v4f*)&mem[mem_base + coff + so + DMEM];
            aO0 = *(const v4f*)&addr[addr_base + coff + so];
            aO1 = *(const v4f*)&addr[addr_base + coff + so + DMEM];
        }
        __syncthreads();
        {
            v8bf af = *(v8bf*)&kb1[(32 * strip + lrow) * LDS_STRIDE + cb];
            v8bf b0 = *(v8bf*)&mb1[lrow * LDS_STRIDE + cb];
            v8bf b1 = *(v8bf*)&mb1[(32 + lrow) * LDS_STRIDE + cb];
            acc0 = __builtin_amdgcn_mfma_f32_32x32x16_bf16(af, b0, acc0, 0, 0, 0);
            acc1 = __builtin_amdgcn_mfma_f32_32x32x16_bf16(af, b1, acc1, 0, 0, 0);
        }
    }

    __syncthreads();  // drain frag reads; reuse staging LDS
    float* red = (float*)smem;  // [64 e][stride 68] floats = 17408 B
#pragma unroll
    for (int i = 0; i < 4; ++i) norm_s[v * 64 + d0 + i] = nacc[i];
    if (kh == 1) {
#pragma unroll
        for (int r = 0; r < 16; ++r) {
            int row = (r & 3) + 8 * (r >> 2) + 4 * lh;
            int d = 32 * strip + row;
            red[lrow * 68 + d] = acc0[r];          // e=lrow
            red[(32 + lrow) * 68 + d] = acc1[r];   // e=32+lrow
        }
    }
    __syncthreads();
    if (kh == 0) {
#pragma unroll
        for (int r = 0; r < 16; ++r) {
            int row = (r & 3) + 8 * (r >> 2) + 4 * lh;
            int d = 32 * strip + row;
            red[lrow * 68 + d] += acc0[r];
            red[(32 + lrow) * 68 + d] += acc1[r];
        }
    }
    __syncthreads();
    // coalesced transposed write-out: pmat[s][b][e][d]
    {
        float* pm = pmat + ((size_t)s * BATCH + b) * 4096;
        const int e = t >> 2;
        const int ds = (t & 3) * 16;
#pragma unroll
        for (int j = 0; j < 4; ++j)
            *(v4f*)&pm[e * 64 + ds + 4 * j] = *(v4f*)&red[e * 68 + ds + 4 * j];
    }
    if (t < 64) {
        float ssum = 0.f;
#pragma unroll
        for (int g = 0; g < 16; ++g) ssum += norm_s[g * 64 + t];
        pnorm[((size_t)s * BATCH + b) * 64 + t] = ssum;
    }
}

// ---------------------------------------------------------------------------
// stage2: 512 blocks = (b, e-quarter). Reduces pmat/pnorm/qa partials, then
// attn[h][e] = (qa[h]·mat[e,:]) / (qa[h]·nrm + 1e-5). One output per thread.
// ---------------------------------------------------------------------------
__global__ __launch_bounds__(256) void stage2(const float* __restrict__ pmat,
                                              const float* __restrict__ pnorm,
                                              const float* __restrict__ qa_p,
                                              const float* __restrict__ bq,
                                              float* __restrict__ attn) {
    __shared__ float mat_s[16 * 68];
    __shared__ float qa_s[16 * 68];
    __shared__ float nrm_s[64];
    const int t = threadIdx.x;
    const int b = blockIdx.x >> 2;
    const int eq = blockIdx.x & 3;

    {   // matrix e-quarter: 1024 contiguous floats per split (transposed layout)
        const int i4 = t * 4;
        v4f acc = (v4f){0.f, 0.f, 0.f, 0.f};
#pragma unroll
        for (int s = 0; s < S1; ++s)
            acc += *(const v4f*)&pmat[((size_t)s * BATCH + b) * 4096 + eq * 1024 + i4];
        *(v4f*)&mat_s[(i4 >> 6) * 68 + (i4 & 63)] = acc;
    }
#pragma unroll
    for (int i = 0; i < 4; ++i) {  // qa reduce + bias + relu
        const int idx = t + 256 * i;
        float ssum = 0.f;
#pragma unroll
        for (int ks = 0; ks < 8; ++ks)
            ssum += qa_p[((size_t)ks * BATCH + b) * DMODEL + idx];
        qa_s[(idx >> 6) * 68 + (idx & 63)] = fmaxf(ssum + bq[idx], 0.f);
    }
    if (t < 64) {
        float ssum = 0.f;
#pragma unroll
        for (int s = 0; s < S1; ++s)
            ssum += pnorm[((size_t)s * BATCH + b) * 64 + t];
        nrm_s[t] = ssum;
    }
    __syncthreads();

    const int h = t >> 4;
    const int e = t & 15;
    float num = 0.f, den = 0.f;
#pragma unroll 8
    for (int d = 0; d < 64; ++d) {
        float q = qa_s[h * 68 + d];
        num = fmaf(q, mat_s[e * 68 + d], num);
        den = fmaf(q, nrm_s[d], den);
    }
    attn[(size_t)b * DMODEL + h * 64 + eq * 16 + e] = num / (den + 1e-5f);
}

// ---------------------------------------------------------------------------
__global__ __launch_bounds__(256) void gemm_out(const float* __restrict__ A,
                                                const float* __restrict__ W,
                                                float* __restrict__ out_p) {
    __shared__ __align__(16) float smem[2 * 32 * 36];
    const int ks = blockIdx.z;
    gemm_sk(A, W, out_p + (size_t)ks * BATCH * DMODEL,
            blockIdx.x * 32, blockIdx.y * 32, ks * 128, smem);
}

// ---------------------------------------------------------------------------
__global__ __launch_bounds__(256) void combine(const float* __restrict__ out_p,
                                               const float* __restrict__ bm,
                                               float* __restrict__ out) {
    const int i = blockIdx.x * 256 + threadIdx.x;
    float ssum = bm[i & (DMODEL - 1)];
#pragma unroll
    for (int ks = 0; ks < 8; ++ks)
        ssum += out_p[(size_t)ks * BATCH * DMODEL + i];
    out[i] = ssum;
}

// ---------------------------------------------------------------------------
extern "C" void kernel_launch(void* const* d_in, const int* in_sizes, int n_in,
                              void* d_out, int out_size, void* d_ws, size_t ws_size,
                              hipStream_t stream) {
    const float* query     = (const float*)d_in[0];
    const float* addresses = (const float*)d_in[1];
    const float* memories  = (const float*)d_in[2];
    const float* Wq        = (const float*)d_in[3];
    const float* bq        = (const float*)d_in[4];
    const float* Wm        = (const float*)d_in[5];
    const float* bm        = (const float*)d_in[6];
    float* out = (float*)d_out;
    float* ws = (float*)d_ws;

    float* qa_p    = ws;                        // 8*128*1024   = 1048576 f
    float* attn_ws = qa_p + 1048576;            // 128*1024     =  131072 f
    float* pnorm   = attn_ws + 131072;          // 4*128*64     =   32768 f
    float* pmat    = pnorm + 32768;             // 4*128*4096   = 2097152 f
    float* out_p   = pmat + 2097152;            // 8*128*1024   = 1048576 f

    k1<<<dim3(BATCH * S1 + 1024), 256, 0, stream>>>(memories, addresses, pmat,
                                                    pnorm, query, Wq, qa_p);
    stage2<<<dim3(512), 256, 0, stream>>>(pmat, pnorm, qa_p, bq, attn_ws);
    gemm_out<<<dim3(4, 32, 8), 256, 0, stream>>>(attn_ws, Wm, out_p);
    combine<<<dim3(512), 256, 0, stream>>>(out_p, bm, out);
}